// Round 7
// baseline (359.576 us; speedup 1.0000x reference)
//
#include <hip/hip_runtime.h>

#define BTOT 8192
#define SEQ 32
#define IPB 6
#define TPB 128
#define L2E 1.4426950408889634f
#define FSTRIDE 520   // featL row stride
#define VSTRIDE 20    // vbuf row stride

// transpose conv2 weights [c2][ch][ky][kx] -> wt[k*16+c2], k = ch*25+tap
__global__ void prep_w2t(const float* __restrict__ w2, float* __restrict__ wt) {
    int idx = blockIdx.x * blockDim.x + threadIdx.x;
    if (idx < 2400) {
        int k = idx >> 4, c2 = idx & 15;
        wt[idx] = w2[c2 * 150 + k];
    }
}

__global__ __launch_bounds__(TPB, 3) void ltc_fused(
    const float* __restrict__ xin,
    const float* __restrict__ w1, const float* __restrict__ b1,
    const float* __restrict__ b2,
    const float* __restrict__ gleak, const float* __restrict__ vleak, const float* __restrict__ cm,
    const float* __restrict__ sigma, const float* __restrict__ mu, const float* __restrict__ ww,
    const float* __restrict__ erev,
    const float* __restrict__ ssigma, const float* __restrict__ smu, const float* __restrict__ sw,
    const float* __restrict__ serev,
    const float* __restrict__ inw, const float* __restrict__ inb,
    const float* __restrict__ outw, const float* __restrict__ outb,
    const float* __restrict__ mask, const float* __restrict__ smask,
    const float* __restrict__ wt,
    float* __restrict__ dout)
{
    // uni: conv scratch (img 1232 + c1p 1440 = 2672 floats),
    // overlaid after conv by compacted params: cR 20 slots x 19 x float4 (1520 f)
    //                                        + cS 16 slots x 19 x float4 (1216 f)
    __shared__ __align__(16) float uni[2736];
    __shared__ __align__(16) float featL[IPB * FSTRIDE];
    __shared__ __align__(16) float vbuf[IPB * VSTRIDE];
    __shared__ int ncol[19], mcol[19], cnts[2];

    float* img = uni;            // 28 x 44
    float* c1p = uni + 1232;     // 6 x 12 x 20
    float4* cR = (float4*)uni;          // [slot][19] {A, B, Z, bits(i*4)}
    float4* cS = ((float4*)uni) + 20 * 19;

    const int tid = threadIdx.x;
    const int b0 = blockIdx.x * IPB;

    // ---------------- conv phase (R4-proven) ----------------
    for (int k = 0; k < IPB; ++k) {
        const int bG = b0 + k;
        const bool valid = bG < BTOT;
        if (valid) {
            for (int idx = tid; idx < 1232; idx += TPB) img[idx] = xin[bG * 1232 + idx];
        }
        __syncthreads();
        if (valid) {
            for (int idx = tid; idx < 240; idx += TPB) {
                int y = idx / 20, xx = idx - (idx / 20) * 20;
                const float* ib = img + (2 * y) * 44 + 2 * xx;
                float win[6][6];
                #pragma unroll
                for (int r = 0; r < 6; ++r) {
                    float2 a = *(const float2*)(ib + r * 44);
                    float2 b = *(const float2*)(ib + r * 44 + 2);
                    float2 c = *(const float2*)(ib + r * 44 + 4);
                    win[r][0] = a.x; win[r][1] = a.y; win[r][2] = b.x;
                    win[r][3] = b.y; win[r][4] = c.x; win[r][5] = c.y;
                }
                for (int ch = 0; ch < 6; ++ch) {
                    const float* wp = w1 + ch * 25;
                    float a00 = 0.f, a01 = 0.f, a10 = 0.f, a11 = 0.f;
                    #pragma unroll
                    for (int ky = 0; ky < 5; ++ky)
                        #pragma unroll
                        for (int kx = 0; kx < 5; ++kx) {
                            float wv = wp[ky * 5 + kx];
                            a00 = fmaf(wv, win[ky][kx], a00);
                            a01 = fmaf(wv, win[ky][kx + 1], a01);
                            a10 = fmaf(wv, win[ky + 1][kx], a10);
                            a11 = fmaf(wv, win[ky + 1][kx + 1], a11);
                        }
                    float m = fmaxf(fmaxf(a00, a01), fmaxf(a10, a11)) + b1[ch];
                    c1p[ch * 240 + idx] = fmaxf(m, 0.f);
                }
            }
        }
        __syncthreads();
        if (valid) {
            const int oy = tid >> 4, ox = tid & 15;
            float acc[16];
            #pragma unroll
            for (int c2 = 0; c2 < 16; ++c2) acc[c2] = 0.f;
            for (int ch = 0; ch < 6; ++ch) {
                const float* rowb = c1p + ch * 240 + oy * 20 + ox;
                const float* wch = wt + (ch * 25 << 4);
                #pragma unroll
                for (int ky = 0; ky < 5; ++ky) {
                    #pragma unroll
                    for (int kx = 0; kx < 5; ++kx) {
                        float xv = rowb[ky * 20 + kx];
                        const float4* wk = (const float4*)(wch + ((ky * 5 + kx) << 4));
                        float4 wa = wk[0], wb = wk[1], wc = wk[2], wd = wk[3];
                        acc[0]  = fmaf(wa.x, xv, acc[0]);  acc[1]  = fmaf(wa.y, xv, acc[1]);
                        acc[2]  = fmaf(wa.z, xv, acc[2]);  acc[3]  = fmaf(wa.w, xv, acc[3]);
                        acc[4]  = fmaf(wb.x, xv, acc[4]);  acc[5]  = fmaf(wb.y, xv, acc[5]);
                        acc[6]  = fmaf(wb.z, xv, acc[6]);  acc[7]  = fmaf(wb.w, xv, acc[7]);
                        acc[8]  = fmaf(wc.x, xv, acc[8]);  acc[9]  = fmaf(wc.y, xv, acc[9]);
                        acc[10] = fmaf(wc.z, xv, acc[10]); acc[11] = fmaf(wc.w, xv, acc[11]);
                        acc[12] = fmaf(wd.x, xv, acc[12]); acc[13] = fmaf(wd.y, xv, acc[13]);
                        acc[14] = fmaf(wd.z, xv, acc[14]); acc[15] = fmaf(wd.w, xv, acc[15]);
                    }
                }
            }
            const bool wl = ((tid & 1) == 0) && ((tid & 16) == 0);
            const int obase = k * FSTRIDE + (oy >> 1) * 8 + (ox >> 1);
            #pragma unroll
            for (int c2 = 0; c2 < 16; ++c2) {
                float a = acc[c2];
                a = fmaxf(a, __shfl_xor(a, 1));
                a = fmaxf(a, __shfl_xor(a, 16));
                if (wl) featL[obase + c2 * 32] = fmaxf(a + b2[c2], 0.f);
            }
        }
        __syncthreads();
    }

    // ---------------- build compacted param lists (overlays conv scratch) ----------------
    for (int idx = tid; idx < 2736; idx += TPB) uni[idx] = 0.f;
    if (tid < IPB * VSTRIDE) vbuf[tid] = 0.f;
    __syncthreads();
    if (tid < 19) {
        const int j = tid;
        int c = 0;
        for (int i = 0; i < 19; ++i) {
            int idx = i * 19 + j;
            if (mask[idx] != 0.f) {
                float s = sigma[idx];
                cR[c * 19 + j] = make_float4(-L2E * s, L2E * s * mu[idx],
                                             ww[idx] * erev[idx], __int_as_float(i * 4));
                ++c;
            }
        }
        ncol[j] = c;
        c = 0;
        for (int i = 0; i < 16; ++i) {
            int idx = i * 19 + j;
            if (smask[idx] != 0.f) {
                float s = ssigma[idx];
                cS[c * 19 + j] = make_float4(-L2E * s * inw[i],
                                             -L2E * s * (inb[i] - smu[idx]),
                                             sw[idx] * serev[idx], __int_as_float(i * 4));
                ++c;
            }
        }
        mcol[j] = c;
    }
    __syncthreads();
    if (tid == 0) {
        int MR = 0, MS = 0;
        for (int j2 = 0; j2 < 19; ++j2) {
            MR = max(MR, ncol[j2]);
            MS = max(MS, mcol[j2]);
        }
        cnts[0] = (MR + 1) & ~1;
        cnts[1] = (MS + 1) & ~1;
    }
    __syncthreads();
    const int MR = __builtin_amdgcn_readfirstlane(cnts[0]);
    const int MS = __builtin_amdgcn_readfirstlane(cnts[1]);

    // ---------------- LTC: 19 lanes/image, 3 images/wave, compacted+paired ----------------
    const int wv_ = tid >> 6, l = tid & 63;
    const int g = l / 19;                 // 0..2 active, 3 = idle tail
    const int j = l - g * 19;             // 0..18
    const int kimg = wv_ * 3 + g;
    const bool act = (g < 3) && (b0 + kimg < BTOT);
    const int kc = (kimg < IPB) ? kimg : (IPB - 1);

    const float gl = gleak[j];
    const float gv = gl * vleak[j];
    const float cmt = cm[j] * 6.f;        // cm / (dt/unfolds), dt=1, unfolds=6

    float v = 0.f;
    const char* frowb = (const char*)(featL + kc * FSTRIDE);
    const char* vrowb = (const char*)(vbuf + kc * VSTRIDE);

    #pragma unroll 1
    for (int st = 0; st < SEQ; ++st) {
        const char* fb = frowb + (st << 6);
        float wns = 0.f, wds = 0.f;
        #pragma unroll 1
        for (int c = 0; c < MS; c += 2) {
            float4 pa = cS[c * 19 + j];
            float4 pb = cS[(c + 1) * 19 + j];
            float fa = *(const float*)(fb + __float_as_int(pa.w));
            float fbv = *(const float*)(fb + __float_as_int(pb.w));
            float ta = fmaf(pa.x, fa, pa.y);
            float tb = fmaf(pb.x, fbv, pb.y);
            float qa = 1.f + __builtin_amdgcn_exp2f(ta);
            float qb = 1.f + __builtin_amdgcn_exp2f(tb);
            float rr = __builtin_amdgcn_rcpf(qa * qb);
            float cn = fmaf(pa.z, qb, pb.z * qa);
            float cd = fmaf(fabsf(pa.z), qb, fabsf(pb.z) * qa);
            wns = fmaf(cn, rr, wns);
            wds = fmaf(cd, rr, wds);
        }
        const float nb = gv + wns;
        const float db = cmt + gl + wds;
        #pragma unroll 1
        for (int u = 0; u < 6; ++u) {
            float num = fmaf(cmt, v, nb);
            float den = db;
            #pragma unroll 1
            for (int c = 0; c < MR; c += 2) {
                float4 pa = cR[c * 19 + j];
                float4 pb = cR[(c + 1) * 19 + j];
                float va = *(const float*)(vrowb + __float_as_int(pa.w));
                float vb = *(const float*)(vrowb + __float_as_int(pb.w));
                float ta = fmaf(pa.x, va, pa.y);
                float tb = fmaf(pb.x, vb, pb.y);
                float qa = 1.f + __builtin_amdgcn_exp2f(ta);
                float qb = 1.f + __builtin_amdgcn_exp2f(tb);
                float rr = __builtin_amdgcn_rcpf(qa * qb);
                float cn = fmaf(pa.z, qb, pb.z * qa);
                float cd = fmaf(fabsf(pa.z), qb, fabsf(pb.z) * qa);
                num = fmaf(cn, rr, num);
                den = fmaf(cd, rr, den);
            }
            v = num * __builtin_amdgcn_rcpf(den + 1e-8f);
            __builtin_amdgcn_wave_barrier();
            __asm__ volatile("" ::: "memory");
            if (act) vbuf[kimg * VSTRIDE + j] = v;
            __builtin_amdgcn_wave_barrier();
            __asm__ volatile("" ::: "memory");
        }
    }
    if (act && j < 2) dout[(b0 + kimg) * 2 + j] = fmaf(v, outw[j], outb[j]);
}

extern "C" void kernel_launch(void* const* d_in, const int* in_sizes, int n_in,
                              void* d_out, int out_size, void* d_ws, size_t ws_size,
                              hipStream_t stream) {
    const float* x      = (const float*)d_in[0];
    const float* w1     = (const float*)d_in[1];
    const float* b1     = (const float*)d_in[2];
    const float* w2     = (const float*)d_in[3];
    const float* b2     = (const float*)d_in[4];
    const float* gleak  = (const float*)d_in[5];
    const float* vleak  = (const float*)d_in[6];
    const float* cm     = (const float*)d_in[7];
    const float* sigma  = (const float*)d_in[8];
    const float* mu     = (const float*)d_in[9];
    const float* ww     = (const float*)d_in[10];
    const float* erev   = (const float*)d_in[11];
    const float* ssig   = (const float*)d_in[12];
    const float* smu    = (const float*)d_in[13];
    const float* sw     = (const float*)d_in[14];
    const float* serev  = (const float*)d_in[15];
    const float* inw    = (const float*)d_in[16];
    const float* inb    = (const float*)d_in[17];
    const float* outw   = (const float*)d_in[18];
    const float* outb   = (const float*)d_in[19];
    const float* mask   = (const float*)d_in[20];
    const float* smask  = (const float*)d_in[21];
    float* wt = (float*)d_ws;   // 2400 floats

    hipLaunchKernelGGL(prep_w2t, dim3(10), dim3(256), 0, stream, w2, wt);

    dim3 grid((BTOT + IPB - 1) / IPB), block(TPB);
    hipLaunchKernelGGL(ltc_fused, grid, block, 0, stream,
                       x, w1, b1, b2, gleak, vleak, cm, sigma, mu, ww, erev,
                       ssig, smu, sw, serev, inw, inb, outw, outb, mask, smask,
                       (const float*)wt, (float*)d_out);
}

// Round 8
// 308.213 us; speedup vs baseline: 1.1666x; 1.1666x over previous
//
#include <hip/hip_runtime.h>

#define BTOT 8192
#define SEQ 32
#define IPB 6
#define TPB 128
#define L2E 1.4426950408889634f
#define FSTRIDE 520   // featL row stride
#define RSL 16        // recurrent param register slots (tail loop covers overflow)

// transpose conv2 weights [c2][ch][ky][kx] -> wt[k*16+c2], k = ch*25+tap
__global__ void prep_w2t(const float* __restrict__ w2, float* __restrict__ wt) {
    int idx = blockIdx.x * blockDim.x + threadIdx.x;
    if (idx < 2400) {
        int k = idx >> 4, c2 = idx & 15;
        wt[idx] = w2[c2 * 150 + k];
    }
}

__global__ __launch_bounds__(TPB, 3) void ltc_fused(
    const float* __restrict__ xin,
    const float* __restrict__ w1, const float* __restrict__ b1,
    const float* __restrict__ b2,
    const float* __restrict__ gleak, const float* __restrict__ vleak, const float* __restrict__ cm,
    const float* __restrict__ sigma, const float* __restrict__ mu, const float* __restrict__ ww,
    const float* __restrict__ erev,
    const float* __restrict__ ssigma, const float* __restrict__ smu, const float* __restrict__ sw,
    const float* __restrict__ serev,
    const float* __restrict__ inw, const float* __restrict__ inb,
    const float* __restrict__ outw, const float* __restrict__ outb,
    const float* __restrict__ mask, const float* __restrict__ smask,
    const float* __restrict__ wt,
    float* __restrict__ dout)
{
    // uni: conv scratch (img 1232 + c1p 1440 = 2672 floats),
    // overlaid after conv by compacted packed param planes (2736 floats):
    //   rAB float2[380], rZI float2[380], sAB float2[304], sZI float2[304]
    __shared__ __align__(16) float uni[2736];
    __shared__ __align__(16) float featL[IPB * FSTRIDE];
    __shared__ int ncol[19], mcol[19], cnts[2];

    float* img = uni;            // 28 x 44
    float* c1p = uni + 1232;     // 6 x 12 x 20
    float2* rAB = (float2*)uni;            // [slot*19+j] {-L2E*sig, L2E*sig*mu}
    float2* rZI = (float2*)(uni + 760);    // [slot*19+j] {w*erev, bits(i)}
    float2* sAB = (float2*)(uni + 1520);
    float2* sZI = (float2*)(uni + 2128);

    const int tid = threadIdx.x;
    const int b0 = blockIdx.x * IPB;

    // ---------------- conv phase (R4-proven) ----------------
    for (int k = 0; k < IPB; ++k) {
        const int bG = b0 + k;
        const bool valid = bG < BTOT;
        if (valid) {
            for (int idx = tid; idx < 1232; idx += TPB) img[idx] = xin[bG * 1232 + idx];
        }
        __syncthreads();
        if (valid) {
            for (int idx = tid; idx < 240; idx += TPB) {
                int y = idx / 20, xx = idx - (idx / 20) * 20;
                const float* ib = img + (2 * y) * 44 + 2 * xx;
                float win[6][6];
                #pragma unroll
                for (int r = 0; r < 6; ++r) {
                    float2 a = *(const float2*)(ib + r * 44);
                    float2 b = *(const float2*)(ib + r * 44 + 2);
                    float2 c = *(const float2*)(ib + r * 44 + 4);
                    win[r][0] = a.x; win[r][1] = a.y; win[r][2] = b.x;
                    win[r][3] = b.y; win[r][4] = c.x; win[r][5] = c.y;
                }
                for (int ch = 0; ch < 6; ++ch) {
                    const float* wp = w1 + ch * 25;
                    float a00 = 0.f, a01 = 0.f, a10 = 0.f, a11 = 0.f;
                    #pragma unroll
                    for (int ky = 0; ky < 5; ++ky)
                        #pragma unroll
                        for (int kx = 0; kx < 5; ++kx) {
                            float wv = wp[ky * 5 + kx];
                            a00 = fmaf(wv, win[ky][kx], a00);
                            a01 = fmaf(wv, win[ky][kx + 1], a01);
                            a10 = fmaf(wv, win[ky + 1][kx], a10);
                            a11 = fmaf(wv, win[ky + 1][kx + 1], a11);
                        }
                    float m = fmaxf(fmaxf(a00, a01), fmaxf(a10, a11)) + b1[ch];
                    c1p[ch * 240 + idx] = fmaxf(m, 0.f);
                }
            }
        }
        __syncthreads();
        if (valid) {
            const int oy = tid >> 4, ox = tid & 15;
            float acc[16];
            #pragma unroll
            for (int c2 = 0; c2 < 16; ++c2) acc[c2] = 0.f;
            for (int ch = 0; ch < 6; ++ch) {
                const float* rowb = c1p + ch * 240 + oy * 20 + ox;
                const float* wch = wt + (ch * 25 << 4);
                #pragma unroll
                for (int ky = 0; ky < 5; ++ky) {
                    #pragma unroll
                    for (int kx = 0; kx < 5; ++kx) {
                        float xv = rowb[ky * 20 + kx];
                        const float4* wk = (const float4*)(wch + ((ky * 5 + kx) << 4));
                        float4 wa = wk[0], wb = wk[1], wc = wk[2], wd = wk[3];
                        acc[0]  = fmaf(wa.x, xv, acc[0]);  acc[1]  = fmaf(wa.y, xv, acc[1]);
                        acc[2]  = fmaf(wa.z, xv, acc[2]);  acc[3]  = fmaf(wa.w, xv, acc[3]);
                        acc[4]  = fmaf(wb.x, xv, acc[4]);  acc[5]  = fmaf(wb.y, xv, acc[5]);
                        acc[6]  = fmaf(wb.z, xv, acc[6]);  acc[7]  = fmaf(wb.w, xv, acc[7]);
                        acc[8]  = fmaf(wc.x, xv, acc[8]);  acc[9]  = fmaf(wc.y, xv, acc[9]);
                        acc[10] = fmaf(wc.z, xv, acc[10]); acc[11] = fmaf(wc.w, xv, acc[11]);
                        acc[12] = fmaf(wd.x, xv, acc[12]); acc[13] = fmaf(wd.y, xv, acc[13]);
                        acc[14] = fmaf(wd.z, xv, acc[14]); acc[15] = fmaf(wd.w, xv, acc[15]);
                    }
                }
            }
            const bool wl = ((tid & 1) == 0) && ((tid & 16) == 0);
            const int obase = k * FSTRIDE + (oy >> 1) * 8 + (ox >> 1);
            #pragma unroll
            for (int c2 = 0; c2 < 16; ++c2) {
                float a = acc[c2];
                a = fmaxf(a, __shfl_xor(a, 1));
                a = fmaxf(a, __shfl_xor(a, 16));
                if (wl) featL[obase + c2 * 32] = fmaxf(a + b2[c2], 0.f);
            }
        }
        __syncthreads();
    }

    // ---------------- build compacted packed param planes ----------------
    for (int idx = tid; idx < 2736; idx += TPB) uni[idx] = 0.f;
    __syncthreads();
    if (tid < 19) {
        const int jj = tid;
        int c = 0;
        for (int i = 0; i < 19; ++i) {
            int idx = i * 19 + jj;
            if (mask[idx] != 0.f) {
                float s = sigma[idx];
                rAB[c * 19 + jj] = make_float2(-L2E * s, L2E * s * mu[idx]);
                rZI[c * 19 + jj] = make_float2(ww[idx] * erev[idx], __int_as_float(i));
                ++c;
            }
        }
        ncol[jj] = c;
        c = 0;
        for (int i = 0; i < 16; ++i) {
            int idx = i * 19 + jj;
            if (smask[idx] != 0.f) {
                float s = ssigma[idx];
                sAB[c * 19 + jj] = make_float2(-L2E * s * inw[i],
                                               -L2E * s * (inb[i] - smu[idx]));
                sZI[c * 19 + jj] = make_float2(sw[idx] * serev[idx], __int_as_float(i));
                ++c;
            }
        }
        mcol[jj] = c;
    }
    __syncthreads();
    if (tid == 0) {
        int MRv = 0, MSv = 0;
        for (int j2 = 0; j2 < 19; ++j2) {
            MRv = max(MRv, ncol[j2]);
            MSv = max(MSv, mcol[j2]);
        }
        cnts[0] = MRv;
        cnts[1] = MSv;
    }
    __syncthreads();
    const int MR = __builtin_amdgcn_readfirstlane(cnts[0]);
    const int MS = __builtin_amdgcn_readfirstlane(cnts[1]);

    // ---------------- LTC: 19 lanes/image, 3 images/wave, shfl exchange ----------------
    const int wv_ = tid >> 6, l = tid & 63;
    const int g = l / 19;                 // 0..2 active, 3 = idle tail
    const int j = l - g * 19;             // 0..18
    const int gbase = g * 19;
    const int kimg = wv_ * 3 + g;
    const bool act = (g < 3) && (b0 + kimg < BTOT);
    const int kc = (kimg < IPB) ? kimg : (IPB - 1);

    // 16 compacted recurrent sites in true VGPRs (48 + 16 regs)
    float UA[RSL], UB[RSL], UZ[RSL];
    int LI[RSL];
    #pragma unroll
    for (int c = 0; c < RSL; ++c) {
        float2 ab = rAB[c * 19 + j];
        float2 zi = rZI[c * 19 + j];
        UA[c] = ab.x;
        UB[c] = ab.y;
        UZ[c] = zi.x;
        LI[c] = gbase + __float_as_int(zi.y);
    }
    #pragma unroll
    for (int c = 0; c < RSL; ++c)
        asm volatile("" : "+v"(UA[c]), "+v"(UB[c]), "+v"(UZ[c]), "+v"(LI[c]));

    const float gl = gleak[j];
    const float gv = gl * vleak[j];
    const float cmt = cm[j] * 6.f;        // cm / (dt/unfolds), dt=1, unfolds=6

    float v = 0.f;
    const float* frow = featL + kc * FSTRIDE;

    #pragma unroll 1
    for (int st = 0; st < SEQ; ++st) {
        const float* fb = frow + st * 16;
        float wns = 0.f, wds = 0.f;
        #pragma unroll 1
        for (int c = 0; c < MS; ++c) {
            float2 ab = sAB[c * 19 + j];
            float2 zi = sZI[c * 19 + j];
            float f = fb[__float_as_int(zi.y)];
            float t = fmaf(ab.x, f, ab.y);
            float r = __builtin_amdgcn_rcpf(1.f + __builtin_amdgcn_exp2f(t));
            wns = fmaf(zi.x, r, wns);
            wds = fmaf(fabsf(zi.x), r, wds);
        }
        const float nb = gv + wns;
        const float db = cmt + gl + wds;
        #pragma unroll 1
        for (int u = 0; u < 6; ++u) {
            float num = fmaf(cmt, v, nb);
            float den = db;
            #pragma unroll
            for (int c = 0; c < RSL; ++c) {
                float vv = __shfl(v, LI[c]);
                float t = fmaf(UA[c], vv, UB[c]);
                float r = __builtin_amdgcn_rcpf(1.f + __builtin_amdgcn_exp2f(t));
                num = fmaf(UZ[c], r, num);
                den = fmaf(fabsf(UZ[c]), r, den);
            }
            #pragma unroll 1
            for (int c = RSL; c < MR; ++c) {   // rare overflow tail
                float2 ab = rAB[c * 19 + j];
                float2 zi = rZI[c * 19 + j];
                float vv = __shfl(v, gbase + __float_as_int(zi.y));
                float t = fmaf(ab.x, vv, ab.y);
                float r = __builtin_amdgcn_rcpf(1.f + __builtin_amdgcn_exp2f(t));
                num = fmaf(zi.x, r, num);
                den = fmaf(fabsf(zi.x), r, den);
            }
            v = num * __builtin_amdgcn_rcpf(den + 1e-8f);
        }
    }
    if (act && j < 2) dout[(b0 + kimg) * 2 + j] = fmaf(v, outw[j], outb[j]);
}

extern "C" void kernel_launch(void* const* d_in, const int* in_sizes, int n_in,
                              void* d_out, int out_size, void* d_ws, size_t ws_size,
                              hipStream_t stream) {
    const float* x      = (const float*)d_in[0];
    const float* w1     = (const float*)d_in[1];
    const float* b1     = (const float*)d_in[2];
    const float* w2     = (const float*)d_in[3];
    const float* b2     = (const float*)d_in[4];
    const float* gleak  = (const float*)d_in[5];
    const float* vleak  = (const float*)d_in[6];
    const float* cm     = (const float*)d_in[7];
    const float* sigma  = (const float*)d_in[8];
    const float* mu     = (const float*)d_in[9];
    const float* ww     = (const float*)d_in[10];
    const float* erev   = (const float*)d_in[11];
    const float* ssig   = (const float*)d_in[12];
    const float* smu    = (const float*)d_in[13];
    const float* sw     = (const float*)d_in[14];
    const float* serev  = (const float*)d_in[15];
    const float* inw    = (const float*)d_in[16];
    const float* inb    = (const float*)d_in[17];
    const float* outw   = (const float*)d_in[18];
    const float* outb   = (const float*)d_in[19];
    const float* mask   = (const float*)d_in[20];
    const float* smask  = (const float*)d_in[21];
    float* wt = (float*)d_ws;   // 2400 floats

    hipLaunchKernelGGL(prep_w2t, dim3(10), dim3(256), 0, stream, w2, wt);

    dim3 grid((BTOT + IPB - 1) / IPB), block(TPB);
    hipLaunchKernelGGL(ltc_fused, grid, block, 0, stream,
                       x, w1, b1, b2, gleak, vleak, cm, sigma, mu, ww, erev,
                       ssig, smu, sw, serev, inw, inb, outw, outb, mask, smask,
                       (const float*)wt, (float*)d_out);
}